// Round 12
// baseline (89.615 us; speedup 1.0000x reference)
//
#include <hip/hip_runtime.h>
#include <hip/hip_bf16.h>

#define T_SEQ 2048
#define EMB   128
#define H     16
#define BATCH 8
#define VSTR  2064        // Vt row stride (elems), non-power-of-2 (r11)
// Q pre-scale: 1/sqrt(16) * log2(e)  -> scores in log2 domain
#define QSCALE 0.360673760222241f

// exp2 via clang builtin (r8-proven); __exp2f clashes with glibc macro.
#define EXP2F(x) __builtin_amdgcn_exp2f(x)

typedef short short8_t __attribute__((ext_vector_type(8)));  // 8 bf16
typedef float f32x4    __attribute__((ext_vector_type(4)));  // MFMA C/D frag

__device__ __forceinline__ unsigned short f2bf(float f) {
    __hip_bfloat16 h = __float2bfloat16(f);
    return *reinterpret_cast<unsigned short*>(&h);
}

// ---------------------------------------------------------------------------
// Kernel 1: QKV projection via MFMA (r8/r11-proven, unchanged).
// ---------------------------------------------------------------------------
__global__ __launch_bounds__(256) void qkv_kernel(
    const float* __restrict__ x,
    const float* __restrict__ Wq,
    const float* __restrict__ Wk,
    const float* __restrict__ Wv,
    unsigned short* __restrict__ Qbf,
    unsigned short* __restrict__ Kbf,
    unsigned short* __restrict__ Vt)
{
    __shared__ unsigned short Wt[3][16][136];

    const int tid = threadIdx.x;
#pragma unroll
    for (int p = 0; p < 6; ++p) {
        const int idx4 = tid + p * 256;
        const int flat = idx4 * 4;
        const int mm   = flat >> 11;
        const int rem  = flat & 2047;
        const int d    = rem >> 4;
        const int c0   = rem & 15;
        const float* Wm = (mm == 0) ? Wq : (mm == 1) ? Wk : Wv;
        float4 w = *reinterpret_cast<const float4*>(Wm + rem);
        Wt[mm][c0    ][d] = f2bf(w.x);
        Wt[mm][c0 + 1][d] = f2bf(w.y);
        Wt[mm][c0 + 2][d] = f2bf(w.z);
        Wt[mm][c0 + 3][d] = f2bf(w.w);
    }
    __syncthreads();

    const int wv   = tid >> 6;
    const int lane = tid & 63;
    const int q    = lane >> 4;
    const int n    = lane & 15;
    const int row0 = blockIdx.x * 64 + wv * 16;
    const float* xr = x + (size_t)(row0 + n) * EMB;

    f32x4 aq = {0,0,0,0}, ak = {0,0,0,0}, av = {0,0,0,0};
#pragma unroll
    for (int t = 0; t < 4; ++t) {
        const int k0 = t * 32 + q * 8;
        float4 xa = *reinterpret_cast<const float4*>(xr + k0);
        float4 xb = *reinterpret_cast<const float4*>(xr + k0 + 4);
        union { unsigned short s[8]; short8_t v; } xf;
        xf.s[0]=f2bf(xa.x); xf.s[1]=f2bf(xa.y); xf.s[2]=f2bf(xa.z); xf.s[3]=f2bf(xa.w);
        xf.s[4]=f2bf(xb.x); xf.s[5]=f2bf(xb.y); xf.s[6]=f2bf(xb.z); xf.s[7]=f2bf(xb.w);
        short8_t wqf = *reinterpret_cast<const short8_t*>(&Wt[0][n][k0]);
        short8_t wkf = *reinterpret_cast<const short8_t*>(&Wt[1][n][k0]);
        short8_t wvf = *reinterpret_cast<const short8_t*>(&Wt[2][n][k0]);
        aq = __builtin_amdgcn_mfma_f32_16x16x32_bf16(xf.v, wqf, aq, 0, 0, 0);
        ak = __builtin_amdgcn_mfma_f32_16x16x32_bf16(xf.v, wkf, ak, 0, 0, 0);
        av = __builtin_amdgcn_mfma_f32_16x16x32_bf16(xf.v, wvf, av, 0, 0, 0);
    }

    const int grow = row0 + q * 4;
    const int b    = grow >> 11;
    const int ib0  = grow & 2047;
#pragma unroll
    for (int r = 0; r < 4; ++r) {
        Qbf[(size_t)(grow + r) * H + n] = f2bf(aq[r] * QSCALE);
        Kbf[(size_t)(grow + r) * H + n] = f2bf(ak[r]);
    }
    union { unsigned short s[4]; unsigned long long u; } vp;
    vp.s[0]=f2bf(av[0]); vp.s[1]=f2bf(av[1]); vp.s[2]=f2bf(av[2]); vp.s[3]=f2bf(av[3]);
    *reinterpret_cast<unsigned long long*>(
        Vt + ((size_t)b * H + n) * VSTR + ib0) = vp.u;
}

// ---------------------------------------------------------------------------
// Kernel 2: full attention with INTRA-BLOCK split-K.
// Grid 256 = (b, qt); 512 threads = 8 waves = 2 groups of 4 waves.
// Group g processes chunks cch = g, g+2, ... (<nc) with r8's online-softmax
// carry; per-chunk body is r10's proven straight line (8 S-MFMAs, mask/max,
// exp2, LDS transpose w/ parity, 4 PV-MFMAs). Groups merge per-row
// (m, l, acc) via LDS + ONE __syncthreads (block-local -> no r9 fence
// poison); group 0 writes the final normalized output (float4).
// ---------------------------------------------------------------------------
__global__ __launch_bounds__(512) void attn_all(
    const unsigned short* __restrict__ Qbf,
    const unsigned short* __restrict__ Kbf,
    const unsigned short* __restrict__ Vt,
    float* __restrict__ out)
{
    __shared__ unsigned int Pbuf[8][2][16][68];   // 69.6 KB (wave, parity)
    __shared__ float Comb[4][16][18];             // 4.6 KB: group-1 partials

    const int b   = blockIdx.x >> 5;
    const int qt  = blockIdx.x & 31;
    const int nc  = (qt >> 1) + 1;                // 128-key chunks for this qt
    const int i0  = qt << 6;

    const int tid  = threadIdx.x;
    const int wv   = tid >> 6;                    // 0..7
    const int grp  = wv >> 2;                     // chunk-group 0/1
    const int wq   = wv & 3;                      // wave within group
    const int lane = tid & 63;
    const int q    = lane >> 4;
    const int n    = lane & 15;
    const int wrow0 = i0 + wq * 16;
    const int irow  = wrow0 + n;

    const unsigned short* Qp = Qbf + (size_t)b * T_SEQ * H;
    const unsigned short* Kp = Kbf + (size_t)b * T_SEQ * H;
    const unsigned short* vrow = Vt + (size_t)b * H * VSTR + (size_t)n * VSTR;

    short8_t qf = {0,0,0,0,0,0,0,0};
    if (q < 2)
        qf = *reinterpret_cast<const short8_t*>(Qp + (size_t)irow * H + q * 8);

    f32x4 acc = {0.f, 0.f, 0.f, 0.f};
    float m = -1e30f, l = 0.f;                    // l: per-quad partial

    int it = 0;
    for (int cch = grp; cch < nc; cch += 2, ++it) {
        const int j0  = cch << 7;
        const int par = it & 1;

        // 8 S-MFMAs; K loads batched (full MLP).
        f32x4 S[8];
#pragma unroll
        for (int s = 0; s < 8; ++s) {
            short8_t kf = {0,0,0,0,0,0,0,0};
            if (q < 2)
                kf = *reinterpret_cast<const short8_t*>(
                        Kp + (size_t)(j0 + s * 16 + n) * H + q * 8);
            f32x4 z = {0.f, 0.f, 0.f, 0.f};
            S[s] = __builtin_amdgcn_mfma_f32_16x16x32_bf16(kf, qf, z, 0, 0, 0);
        }
        // V fragments early (consumed after softmax).
        short8_t vf[4];
#pragma unroll
        for (int h = 0; h < 4; ++h)
            vf[h] = *reinterpret_cast<const short8_t*>(
                        vrow + j0 + h * 32 + q * 8);

        // Causal mask only on the diagonal chunk (wave-uniform) + row max.
        float tm = -1e30f;
        if (j0 + 127 > wrow0) {
#pragma unroll
            for (int s = 0; s < 8; ++s) {
                const int kb = j0 + s * 16 + q * 4;
#pragma unroll
                for (int rr = 0; rr < 4; ++rr) {
                    float v = (kb + rr <= irow) ? S[s][rr] : -1e30f;
                    S[s][rr] = v;
                    tm = fmaxf(tm, v);
                }
            }
        } else {
#pragma unroll
            for (int s = 0; s < 8; ++s)
                tm = fmaxf(tm, fmaxf(fmaxf(S[s][0], S[s][1]),
                                     fmaxf(S[s][2], S[s][3])));
        }
        tm = fmaxf(tm, __shfl_xor(tm, 16));
        tm = fmaxf(tm, __shfl_xor(tm, 32));
        const float mn    = fmaxf(m, tm);
        const float alpha = EXP2F(m - mn);
        m = mn;

        // exp2, per-quad partial sum, pack P^T into this wave's Pbuf.
        float ps = 0.f;
#pragma unroll
        for (int s = 0; s < 8; ++s) {
            float e0 = EXP2F(S[s][0] - mn);
            float e1 = EXP2F(S[s][1] - mn);
            float e2 = EXP2F(S[s][2] - mn);
            float e3 = EXP2F(S[s][3] - mn);
            ps += (e0 + e1) + (e2 + e3);
            unsigned int b0 = __builtin_bit_cast(unsigned int, e0);
            unsigned int b1 = __builtin_bit_cast(unsigned int, e1);
            unsigned int b2 = __builtin_bit_cast(unsigned int, e2);
            unsigned int b3 = __builtin_bit_cast(unsigned int, e3);
            unsigned long long pw =
                (unsigned long long)((b1 & 0xffff0000u) | (b0 >> 16)) |
                ((unsigned long long)((b3 & 0xffff0000u) | (b2 >> 16)) << 32);
            *reinterpret_cast<unsigned long long*>(
                &Pbuf[wv][par][n][8 * s + 2 * q]) = pw;
        }
        l = l * alpha + ps;
        acc[0] *= alpha; acc[1] *= alpha; acc[2] *= alpha; acc[3] *= alpha;

        // PV: O^T += V^T · P^T (4 MFMAs, b128 Pbuf reads).
#pragma unroll
        for (int h = 0; h < 4; ++h) {
            uint4 p4 = *reinterpret_cast<const uint4*>(
                    &Pbuf[wv][par][n][16 * h + 4 * q]);
            union { uint4 u; short8_t v; } pu; pu.u = p4;
            acc = __builtin_amdgcn_mfma_f32_16x16x32_bf16(vf[h], pu.v, acc, 0, 0, 0);
        }
    }

    // Cross-quad l sum (exact; alpha was row-wide each iteration).
    l += __shfl_xor(l, 16);
    l += __shfl_xor(l, 32);

    // Group 1 publishes per-row partials to LDS.
    if (grp == 1) {
        Comb[wq][n][q * 4 + 0] = acc[0];
        Comb[wq][n][q * 4 + 1] = acc[1];
        Comb[wq][n][q * 4 + 2] = acc[2];
        Comb[wq][n][q * 4 + 3] = acc[3];
        if (q == 0) { Comb[wq][n][16] = m; Comb[wq][n][17] = l; }
    }
    __syncthreads();

    // Group 0 merges (log-sum-exp) and writes the final output.
    if (grp == 0) {
        const float m1 = Comb[wq][n][16];
        const float l1 = Comb[wq][n][17];
        const float M  = fmaxf(m, m1);
        const float w0 = EXP2F(m - M);
        const float w1 = EXP2F(m1 - M);          // 0 if group 1 was empty
        const float L  = l * w0 + l1 * w1;
        float4 o;
        o.x = (acc[0] * w0 + Comb[wq][n][q * 4 + 0] * w1) / L;
        o.y = (acc[1] * w0 + Comb[wq][n][q * 4 + 1] * w1) / L;
        o.z = (acc[2] * w0 + Comb[wq][n][q * 4 + 2] * w1) / L;
        o.w = (acc[3] * w0 + Comb[wq][n][q * 4 + 3] * w1) / L;
        *reinterpret_cast<float4*>(
            out + ((size_t)(b * T_SEQ) + irow) * H + q * 4) = o;
    }
}

// ---------------------------------------------------------------------------
extern "C" void kernel_launch(void* const* d_in, const int* in_sizes, int n_in,
                              void* d_out, int out_size, void* d_ws, size_t ws_size,
                              hipStream_t stream)
{
    const float* x  = (const float*)d_in[0];
    const float* Wq = (const float*)d_in[1];
    const float* Wk = (const float*)d_in[2];
    const float* Wv = (const float*)d_in[3];
    float* out = (float*)d_out;

    const size_t NE = (size_t)BATCH * T_SEQ * H;
    unsigned short* Qbf = (unsigned short*)d_ws;
    unsigned short* Kbf = Qbf + NE;
    unsigned short* Vt  = Kbf + NE;               // BATCH*H*VSTR elems

    qkv_kernel<<<BATCH * T_SEQ / 64, 256, 0, stream>>>(
        x, Wq, Wk, Wv, Qbf, Kbf, Vt);
    attn_all<<<BATCH * 32, 512, 0, stream>>>(Qbf, Kbf, Vt, out);
}

// Round 13
// 82.894 us; speedup vs baseline: 1.0811x; 1.0811x over previous
//
#include <hip/hip_runtime.h>
#include <hip/hip_bf16.h>

#define T_SEQ 2048
#define EMB   128
#define H     16
#define BATCH 8
#define MAXP  16          // chunks per row (CHUNK=128)
#define VSTR  2064        // Vt row stride (elems), non-power-of-2 (r11)
#define SLOT  10          // P2 slot: 10 u32 = [8x u32 bf16-pairs][m][l]
// Q pre-scale: 1/sqrt(16) * log2(e)  -> scores in log2 domain
#define QSCALE 0.360673760222241f

// exp2 via clang builtin (r8-proven); __exp2f clashes with glibc macro.
#define EXP2F(x) __builtin_amdgcn_exp2f(x)

typedef short short8_t __attribute__((ext_vector_type(8)));  // 8 bf16
typedef float f32x4    __attribute__((ext_vector_type(4)));  // MFMA C/D frag

__device__ __forceinline__ unsigned short f2bf(float f) {
    __hip_bfloat16 h = __float2bfloat16(f);   // RNE
    return *reinterpret_cast<unsigned short*>(&h);
}

// ---------------------------------------------------------------------------
// Kernel 1: QKV projection via MFMA (r8/r11-proven, unchanged).
// ---------------------------------------------------------------------------
__global__ __launch_bounds__(256) void qkv_kernel(
    const float* __restrict__ x,
    const float* __restrict__ Wq,
    const float* __restrict__ Wk,
    const float* __restrict__ Wv,
    unsigned short* __restrict__ Qbf,
    unsigned short* __restrict__ Kbf,
    unsigned short* __restrict__ Vt)
{
    __shared__ unsigned short Wt[3][16][136];

    const int tid = threadIdx.x;
#pragma unroll
    for (int p = 0; p < 6; ++p) {
        const int idx4 = tid + p * 256;
        const int flat = idx4 * 4;
        const int mm   = flat >> 11;
        const int rem  = flat & 2047;
        const int d    = rem >> 4;
        const int c0   = rem & 15;
        const float* Wm = (mm == 0) ? Wq : (mm == 1) ? Wk : Wv;
        float4 w = *reinterpret_cast<const float4*>(Wm + rem);
        Wt[mm][c0    ][d] = f2bf(w.x);
        Wt[mm][c0 + 1][d] = f2bf(w.y);
        Wt[mm][c0 + 2][d] = f2bf(w.z);
        Wt[mm][c0 + 3][d] = f2bf(w.w);
    }
    __syncthreads();

    const int wv   = tid >> 6;
    const int lane = tid & 63;
    const int q    = lane >> 4;
    const int n    = lane & 15;
    const int row0 = blockIdx.x * 64 + wv * 16;
    const float* xr = x + (size_t)(row0 + n) * EMB;

    f32x4 aq = {0,0,0,0}, ak = {0,0,0,0}, av = {0,0,0,0};
#pragma unroll
    for (int t = 0; t < 4; ++t) {
        const int k0 = t * 32 + q * 8;
        float4 xa = *reinterpret_cast<const float4*>(xr + k0);
        float4 xb = *reinterpret_cast<const float4*>(xr + k0 + 4);
        union { unsigned short s[8]; short8_t v; } xf;
        xf.s[0]=f2bf(xa.x); xf.s[1]=f2bf(xa.y); xf.s[2]=f2bf(xa.z); xf.s[3]=f2bf(xa.w);
        xf.s[4]=f2bf(xb.x); xf.s[5]=f2bf(xb.y); xf.s[6]=f2bf(xb.z); xf.s[7]=f2bf(xb.w);
        short8_t wqf = *reinterpret_cast<const short8_t*>(&Wt[0][n][k0]);
        short8_t wkf = *reinterpret_cast<const short8_t*>(&Wt[1][n][k0]);
        short8_t wvf = *reinterpret_cast<const short8_t*>(&Wt[2][n][k0]);
        aq = __builtin_amdgcn_mfma_f32_16x16x32_bf16(xf.v, wqf, aq, 0, 0, 0);
        ak = __builtin_amdgcn_mfma_f32_16x16x32_bf16(xf.v, wkf, ak, 0, 0, 0);
        av = __builtin_amdgcn_mfma_f32_16x16x32_bf16(xf.v, wvf, av, 0, 0, 0);
    }

    const int grow = row0 + q * 4;
    const int b    = grow >> 11;
    const int ib0  = grow & 2047;
#pragma unroll
    for (int r = 0; r < 4; ++r) {
        Qbf[(size_t)(grow + r) * H + n] = f2bf(aq[r] * QSCALE);
        Kbf[(size_t)(grow + r) * H + n] = f2bf(ak[r]);
    }
    union { unsigned short s[4]; unsigned long long u; } vp;
    vp.s[0]=f2bf(av[0]); vp.s[1]=f2bf(av[1]); vp.s[2]=f2bf(av[2]); vp.s[3]=f2bf(av[3]);
    *reinterpret_cast<unsigned long long*>(
        Vt + ((size_t)b * H + n) * VSTR + ib0) = vp.u;
}

// ---------------------------------------------------------------------------
// Kernel 2a: single-shot flash attention chunk (r10/r11-proven structure).
// Grid (272, 8); 4 independent waves; no loop, no barriers. NEW (r13):
// partials stored compact — 16x bf16 acc + fp32 m,l = 40 B/slot.
// ---------------------------------------------------------------------------
__global__ __launch_bounds__(256) void attn_phase1(
    const unsigned short* __restrict__ Qbf,
    const unsigned short* __restrict__ Kbf,
    const unsigned short* __restrict__ Vt,
    unsigned int* __restrict__ P2)
{
    __shared__ unsigned int Pbuf[4][16][68];   // 17.4 KB

    int r = blockIdx.x;
    int qt = 0;
    while (r >= (qt >> 1) + 1) { r -= (qt >> 1) + 1; ++qt; }
    const int cch  = r;
    const int b    = blockIdx.y;
    const int i0   = qt << 6;
    const int j0   = cch << 7;

    const int tid  = threadIdx.x;
    const int wv   = tid >> 6;
    const int lane = tid & 63;
    const int q    = lane >> 4;
    const int n    = lane & 15;
    const int wrow0 = i0 + wv * 16;
    const int irow  = wrow0 + n;

    const unsigned short* Qp = Qbf + (size_t)b * T_SEQ * H;
    const unsigned short* Kp = Kbf + (size_t)b * T_SEQ * H;
    const unsigned short* vrow = Vt + (size_t)b * H * VSTR + (size_t)n * VSTR;

    short8_t qf = {0,0,0,0,0,0,0,0};
    if (q < 2)
        qf = *reinterpret_cast<const short8_t*>(Qp + (size_t)irow * H + q * 8);

    // 8 S-MFMAs; K loads batched (full memory-level parallelism).
    f32x4 S[8];
#pragma unroll
    for (int s = 0; s < 8; ++s) {
        short8_t kf = {0,0,0,0,0,0,0,0};
        if (q < 2)
            kf = *reinterpret_cast<const short8_t*>(
                    Kp + (size_t)(j0 + s * 16 + n) * H + q * 8);
        f32x4 z = {0.f, 0.f, 0.f, 0.f};
        S[s] = __builtin_amdgcn_mfma_f32_16x16x32_bf16(kf, qf, z, 0, 0, 0);
    }
    // V fragments issued early (consumed after softmax).
    short8_t vf[4];
#pragma unroll
    for (int h = 0; h < 4; ++h)
        vf[h] = *reinterpret_cast<const short8_t*>(vrow + j0 + h * 32 + q * 8);

    // Causal mask only on the diagonal chunk (wave-uniform) + row max.
    float tm = -1e30f;
    if (j0 + 127 > wrow0) {
#pragma unroll
        for (int s = 0; s < 8; ++s) {
            const int kb = j0 + s * 16 + q * 4;
#pragma unroll
            for (int rr = 0; rr < 4; ++rr) {
                float v = (kb + rr <= irow) ? S[s][rr] : -1e30f;
                S[s][rr] = v;
                tm = fmaxf(tm, v);
            }
        }
    } else {
#pragma unroll
        for (int s = 0; s < 8; ++s)
            tm = fmaxf(tm, fmaxf(fmaxf(S[s][0], S[s][1]),
                                 fmaxf(S[s][2], S[s][3])));
    }
    tm = fmaxf(tm, __shfl_xor(tm, 16));
    tm = fmaxf(tm, __shfl_xor(tm, 32));
    const float m = tm;

    // exp2, per-quad partial sum, pack P^T into LDS.
    float l = 0.f;
#pragma unroll
    for (int s = 0; s < 8; ++s) {
        float e0 = EXP2F(S[s][0] - m);
        float e1 = EXP2F(S[s][1] - m);
        float e2 = EXP2F(S[s][2] - m);
        float e3 = EXP2F(S[s][3] - m);
        l += (e0 + e1) + (e2 + e3);
        unsigned int b0 = __builtin_bit_cast(unsigned int, e0);
        unsigned int b1 = __builtin_bit_cast(unsigned int, e1);
        unsigned int b2 = __builtin_bit_cast(unsigned int, e2);
        unsigned int b3 = __builtin_bit_cast(unsigned int, e3);
        unsigned long long pw =
            (unsigned long long)((b1 & 0xffff0000u) | (b0 >> 16)) |
            ((unsigned long long)((b3 & 0xffff0000u) | (b2 >> 16)) << 32);
        *reinterpret_cast<unsigned long long*>(&Pbuf[wv][n][8 * s + 2 * q]) = pw;
    }

    // PV: O^T = V^T · P^T (4 MFMAs, b128 Pbuf reads).
    f32x4 acc = {0.f, 0.f, 0.f, 0.f};
#pragma unroll
    for (int h = 0; h < 4; ++h) {
        uint4 p4 = *reinterpret_cast<const uint4*>(&Pbuf[wv][n][16 * h + 4 * q]);
        union { uint4 u; short8_t v; } pu; pu.u = p4;
        acc = __builtin_amdgcn_mfma_f32_16x16x32_bf16(vf[h], pu.v, acc, 0, 0, 0);
    }

    l += __shfl_xor(l, 16);
    l += __shfl_xor(l, 32);

    // Compact partial: lane q writes acc[0..3] as bf16 pairs (one b64);
    // q==0 writes m,l (one b64). Slot = 40 B, 8B-aligned throughout.
    unsigned int* pp = P2 + ((size_t)(b * T_SEQ + irow) * MAXP + cch) * SLOT;
    const unsigned int pa =
        (unsigned int)f2bf(acc[0]) | ((unsigned int)f2bf(acc[1]) << 16);
    const unsigned int pb =
        (unsigned int)f2bf(acc[2]) | ((unsigned int)f2bf(acc[3]) << 16);
    unsigned long long aw = (unsigned long long)pa |
                            ((unsigned long long)pb << 32);
    *reinterpret_cast<unsigned long long*>(pp + 2 * q) = aw;
    if (q == 0) {
        unsigned long long mlw =
            (unsigned long long)__builtin_bit_cast(unsigned int, m) |
            ((unsigned long long)__builtin_bit_cast(unsigned int, l) << 32);
        *reinterpret_cast<unsigned long long*>(pp + 8) = mlw;
    }
}

// ---------------------------------------------------------------------------
// Kernel 2b: combine partials (log2 domain), branchless full unroll (r11)
// on the compact 40 B layout: m/l broadcast-read, acc unpacked from the
// u32 pair containing dim d. exp2(-1e30-M)=0 exactly zeroes invalid slots.
// ---------------------------------------------------------------------------
__global__ __launch_bounds__(256) void attn_phase2(
    const unsigned int* __restrict__ P2, float* __restrict__ out)
{
    const int gid = blockIdx.x * 256 + threadIdx.x;
    const int row = gid >> 4;
    const int d   = gid & 15;
    const int ib  = row & (T_SEQ - 1);
    const int nc  = (ib >> 7) + 1;             // valid chunks for this row
    const unsigned int* base = P2 + (size_t)row * (MAXP * SLOT);
    const int dpair = d >> 1;
    const int dhi   = (d & 1) << 4;            // 0 or 16-bit shift

    float mv[MAXP];
#pragma unroll
    for (int p = 0; p < MAXP; ++p) {
        const float raw = __builtin_bit_cast(float, base[p * SLOT + 8]);
        mv[p] = (p < nc) ? raw : -1e30f;
    }
    float M = -1e30f;
#pragma unroll
    for (int p = 0; p < MAXP; ++p) M = fmaxf(M, mv[p]);

    float L = 0.f, o = 0.f;
#pragma unroll
    for (int p = 0; p < MAXP; ++p) {
        const float wgt = EXP2F(mv[p] - M);    // 0 for invalid slots
        const float lv  = __builtin_bit_cast(float, base[p * SLOT + 9]);
        const unsigned int pr = base[p * SLOT + dpair];
        const float av = __builtin_bit_cast(float, ((pr >> dhi) & 0xffffu) << 16);
        L += wgt * lv;
        o += wgt * av;
    }
    out[gid] = o / L;
}

// ---------------------------------------------------------------------------
extern "C" void kernel_launch(void* const* d_in, const int* in_sizes, int n_in,
                              void* d_out, int out_size, void* d_ws, size_t ws_size,
                              hipStream_t stream)
{
    const float* x  = (const float*)d_in[0];
    const float* Wq = (const float*)d_in[1];
    const float* Wk = (const float*)d_in[2];
    const float* Wv = (const float*)d_in[3];
    float* out = (float*)d_out;

    const size_t NE = (size_t)BATCH * T_SEQ * H;      // 262144 elems per buf
    unsigned short* Qbf = (unsigned short*)d_ws;
    unsigned short* Kbf = Qbf + NE;
    unsigned short* Vt  = Kbf + NE;                   // BATCH*H*VSTR elems
    unsigned int* P2 = (unsigned int*)(Vt + (size_t)BATCH * H * VSTR);

    qkv_kernel<<<BATCH * T_SEQ / 64, 256, 0, stream>>>(
        x, Wq, Wk, Wv, Qbf, Kbf, Vt);
    attn_phase1<<<dim3(272, BATCH), 256, 0, stream>>>(Qbf, Kbf, Vt, P2);
    attn_phase2<<<(int)(NE / 256), 256, 0, stream>>>(P2, out);
}